// Round 12
// baseline (318.532 us; speedup 1.0000x reference)
//
#include <hip/hip_runtime.h>
#include <math.h>

#define BB 32
#define NN 128
#define DD 64
#define EE 5
#define TT 6          // 1+T iterations
#define NE (NN*EE)    // 640
#define RR 8          // rows per block
#define NTH 320       // 5 waves; wave == expert in Phase A
#define MSG_SZ ((size_t)BB*NN*EE*DD)   // 1310720
#define COL_SZ ((size_t)BB*NN*EE)      // 20480
#define PROP_SZ ((size_t)BB*NN*DD)     // 262144

__device__ __forceinline__ float fsig(float x) {
    float t = __expf(-x);
    return __fdividef(1.f, 1.f + t);
}
__device__ __forceinline__ float ftanh_(float x) {
    float xc = fminf(fmaxf(x, -15.f), 15.f);
    float t = __expf(-2.f * xc);
    return 1.f - __fdividef(2.f * t, 1.f + t);
}

#define QFMA(A, sx, M) { A.x=fmaf(sx,(M).x,A.x); A.y=fmaf(sx,(M).y,A.y); \
                         A.z=fmaf(sx,(M).z,A.z); A.w=fmaf(sx,(M).w,A.w); }
#define QSHFL(A, off)  { A.x+=__shfl_xor(A.x,off); A.y+=__shfl_xor(A.y,off); \
                         A.z+=__shfl_xor(A.z,off); A.w+=__shfl_xor(A.w,off); }
#define QDOT(A, W) ((A).x*(W).x + (A).y*(W).y + (A).z*(W).z + (A).w*(W).w)

// ================= per-iteration kernel (8 rows/block, 512 blocks) =================
// k_iter<DO_B,DO_A>: PhaseB(t) (scores->out, merged, GRU) then PhaseA(t+1).
// grid = 512 (2 blocks/CU by 56KB LDS), 320 thr = 5 waves.
// XCD swizzle: all 16 blocks of batch b on XCD b%8 (round-7 validated).
// L2 traffic per dispatch ~172MB (4x less than 2-rows/block).
template<int DO_B, int DO_A>
__global__ void __launch_bounds__(NTH) k_iter(
    const float* __restrict__ propR, float* __restrict__ propW,
    const float* __restrict__ msgR, float* __restrict__ msgW,
    const float* __restrict__ colvR, float* __restrict__ colvW,
    const float* __restrict__ rowvR, float* __restrict__ rowvW,
    const int* __restrict__ mask,
    const float* __restrict__ We, const float* __restrict__ be,
    const float* __restrict__ Wa, const float* __restrict__ ba,
    const float* __restrict__ Wr, const float* __restrict__ br,
    const float* __restrict__ Wz, const float* __restrict__ bz,
    const float* __restrict__ Wh, const float* __restrict__ bh,
    float* __restrict__ out_t)
{
    const int bid = blockIdx.x;
    const int x = bid & 7;             // XCD
    const int s = bid >> 3;            // 0..63
    const int b = x + 8 * (s >> 4);    // 4 batches per XCD
    const int it = s & 15;             // 16 i-tiles per batch
    const int bi0 = b * NN + it * RR;

    const int tid = threadIdx.x;
    const int g = tid >> 6;            // wave 0..4
    const int f = tid & 63;            // lane
    const int lg = f >> 4;             // lane group 0..3
    const int dq = (f & 15) * 4;       // d-quad base

    __shared__ float s_sc[NE][RR];        // 20480 scores [je][q]
    __shared__ float s_pt[DD][RR];        // 2048  prop [d][q]
    __shared__ float s_act[2*DD][RR];     // 4096  [0..63]=merged, [64..127]=prop/rpt
    __shared__ float s_pm[EE][RR][DD];    // 10240 merged partials
    __shared__ float s_g1[EE][RR][DD];    // 10240 gate partial r / h
    __shared__ float s_g2[EE][RR][DD];    // 10240 gate partial z
    __shared__ float s_rv[RR][EE];        // 160

    for (int idx = tid; idx < RR*DD; idx += NTH) {
        int q = idx >> 6, d = idx & 63;
        s_pt[d][q] = propR[(bi0 + q) * DD + d];
    }
    if (DO_B && tid < RR*EE) s_rv[tid/EE][tid%EE] = rowvR[bi0*EE + tid];
    __syncthreads();

    // peeled (q,d) pair assignment for combine phases (no runtime reg-array idx)
    const int qA_ = tid >> 6, dA_ = tid & 63;
    const int idxB_ = tid + NTH;
    const int qB_ = idxB_ >> 6, dB_ = idxB_ & 63;
    const bool hasB = idxB_ < RR*DD;      // tid < 192
    float pA_ = 0.f, pB_ = 0.f, zA_ = 0.f, zB_ = 0.f;

    if (DO_B) {
        // ---- scores -> out + LDS (each thread 2 je values x 8 rows) ----
        #pragma unroll
        for (int jj = 0; jj < 2; ++jj) {
            const int je = tid + jj * NTH;
            const int j = je / EE, e = je - j * EE;
            const float cv = colvR[b*NE + je] + ba[e];
            const int mrow = (b*NN + it*RR) * NN + j;
            #pragma unroll
            for (int qq = 0; qq < RR; ++qq) {
                float sc = fsig(s_rv[qq][e] + cv) * (float)mask[mrow + qq*NN];
                s_sc[je][qq] = sc;
                out_t[(size_t)(bi0+qq)*NE + je] = sc;
            }
        }
        __syncthreads();

        // ---- merged partials: wave g covers je [g*128,+128), lane-quad ----
        {
            const float* mb = msgR + (size_t)b * NE * DD;
            float4 a0={0,0,0,0},a1={0,0,0,0},a2={0,0,0,0},a3={0,0,0,0},
                   a4={0,0,0,0},a5={0,0,0,0},a6={0,0,0,0},a7={0,0,0,0};
            const int je0 = g * 128;
            #pragma unroll 4
            for (int jb = 0; jb < 32; ++jb) {
                const int je = je0 + jb*4 + lg;
                float4 m  = *(const float4*)&mb[(size_t)je*DD + dq];
                float4 sA = *(const float4*)&s_sc[je][0];
                float4 sB = *(const float4*)&s_sc[je][4];
                QFMA(a0,sA.x,m) QFMA(a1,sA.y,m) QFMA(a2,sA.z,m) QFMA(a3,sA.w,m)
                QFMA(a4,sB.x,m) QFMA(a5,sB.y,m) QFMA(a6,sB.z,m) QFMA(a7,sB.w,m)
            }
            QSHFL(a0,16) QSHFL(a1,16) QSHFL(a2,16) QSHFL(a3,16)
            QSHFL(a4,16) QSHFL(a5,16) QSHFL(a6,16) QSHFL(a7,16)
            QSHFL(a0,32) QSHFL(a1,32) QSHFL(a2,32) QSHFL(a3,32)
            QSHFL(a4,32) QSHFL(a5,32) QSHFL(a6,32) QSHFL(a7,32)
            if (lg == 0) {
                *(float4*)&s_pm[g][0][dq] = a0; *(float4*)&s_pm[g][1][dq] = a1;
                *(float4*)&s_pm[g][2][dq] = a2; *(float4*)&s_pm[g][3][dq] = a3;
                *(float4*)&s_pm[g][4][dq] = a4; *(float4*)&s_pm[g][5][dq] = a5;
                *(float4*)&s_pm[g][6][dq] = a6; *(float4*)&s_pm[g][7][dq] = a7;
            }
        }
        __syncthreads();

        // ---- combine merged -> s_act[0..63]; prop -> s_act[64..127] ----
        {
            float m = s_pm[0][qA_][dA_]+s_pm[1][qA_][dA_]+s_pm[2][qA_][dA_]
                    + s_pm[3][qA_][dA_]+s_pm[4][qA_][dA_];
            s_act[dA_][qA_] = m;
            pA_ = s_pt[dA_][qA_];
            s_act[DD+dA_][qA_] = pA_;
            if (hasB) {
                float mB = s_pm[0][qB_][dB_]+s_pm[1][qB_][dB_]+s_pm[2][qB_][dB_]
                         + s_pm[3][qB_][dB_]+s_pm[4][qB_][dB_];
                s_act[dB_][qB_] = mB;
                pB_ = s_pt[dB_][qB_];
                s_act[DD+dB_][qB_] = pB_;
            }
        }
        __syncthreads();

        // ---- gates r,z: wave g covers k in [(g*128)/5,((g+1)*128)/5) ----
        {
            const int kb0 = (g * 2*DD) / EE, kb1 = ((g+1) * 2*DD) / EE;
            float r0=0,r1=0,r2=0,r3=0,r4=0,r5=0,r6=0,r7=0;
            float z0=0,z1=0,z2=0,z3=0,z4=0,z5=0,z6=0,z7=0;
            for (int k = kb0; k < kb1; ++k) {
                float wr = Wr[k*DD + f], wz = Wz[k*DD + f];
                float4 vA = *(const float4*)&s_act[k][0];
                float4 vB = *(const float4*)&s_act[k][4];
                r0=fmaf(vA.x,wr,r0); r1=fmaf(vA.y,wr,r1); r2=fmaf(vA.z,wr,r2); r3=fmaf(vA.w,wr,r3);
                r4=fmaf(vB.x,wr,r4); r5=fmaf(vB.y,wr,r5); r6=fmaf(vB.z,wr,r6); r7=fmaf(vB.w,wr,r7);
                z0=fmaf(vA.x,wz,z0); z1=fmaf(vA.y,wz,z1); z2=fmaf(vA.z,wz,z2); z3=fmaf(vA.w,wz,z3);
                z4=fmaf(vB.x,wz,z4); z5=fmaf(vB.y,wz,z5); z6=fmaf(vB.z,wz,z6); z7=fmaf(vB.w,wz,z7);
            }
            s_g1[g][0][f]=r0; s_g1[g][1][f]=r1; s_g1[g][2][f]=r2; s_g1[g][3][f]=r3;
            s_g1[g][4][f]=r4; s_g1[g][5][f]=r5; s_g1[g][6][f]=r6; s_g1[g][7][f]=r7;
            s_g2[g][0][f]=z0; s_g2[g][1][f]=z1; s_g2[g][2][f]=z2; s_g2[g][3][f]=z3;
            s_g2[g][4][f]=z4; s_g2[g][5][f]=z5; s_g2[g][6][f]=z6; s_g2[g][7][f]=z7;
        }
        __syncthreads();

        // ---- combine r,z; write r*prop into s_act[64..127] ----
        {
            float ar = br[dA_] + s_g1[0][qA_][dA_]+s_g1[1][qA_][dA_]+s_g1[2][qA_][dA_]
                                + s_g1[3][qA_][dA_]+s_g1[4][qA_][dA_];
            float az = bz[dA_] + s_g2[0][qA_][dA_]+s_g2[1][qA_][dA_]+s_g2[2][qA_][dA_]
                                + s_g2[3][qA_][dA_]+s_g2[4][qA_][dA_];
            zA_ = fsig(az);
            s_act[DD+dA_][qA_] = fsig(ar) * pA_;
            if (hasB) {
                float arB = br[dB_] + s_g1[0][qB_][dB_]+s_g1[1][qB_][dB_]+s_g1[2][qB_][dB_]
                                     + s_g1[3][qB_][dB_]+s_g1[4][qB_][dB_];
                float azB = bz[dB_] + s_g2[0][qB_][dB_]+s_g2[1][qB_][dB_]+s_g2[2][qB_][dB_]
                                     + s_g2[3][qB_][dB_]+s_g2[4][qB_][dB_];
                zB_ = fsig(azB);
                s_act[DD+dB_][qB_] = fsig(arB) * pB_;
            }
        }
        __syncthreads();

        // ---- gate h: same k-split over [merged | r*prop] ----
        {
            const int kb0 = (g * 2*DD) / EE, kb1 = ((g+1) * 2*DD) / EE;
            float h0=0,h1=0,h2=0,h3=0,h4=0,h5=0,h6=0,h7=0;
            for (int k = kb0; k < kb1; ++k) {
                float wh = Wh[k*DD + f];
                float4 vA = *(const float4*)&s_act[k][0];
                float4 vB = *(const float4*)&s_act[k][4];
                h0=fmaf(vA.x,wh,h0); h1=fmaf(vA.y,wh,h1); h2=fmaf(vA.z,wh,h2); h3=fmaf(vA.w,wh,h3);
                h4=fmaf(vB.x,wh,h4); h5=fmaf(vB.y,wh,h5); h6=fmaf(vB.z,wh,h6); h7=fmaf(vB.w,wh,h7);
            }
            s_g1[g][0][f]=h0; s_g1[g][1][f]=h1; s_g1[g][2][f]=h2; s_g1[g][3][f]=h3;
            s_g1[g][4][f]=h4; s_g1[g][5][f]=h5; s_g1[g][6][f]=h6; s_g1[g][7][f]=h7;
        }
        __syncthreads();

        // ---- final: h, prop update ----
        {
            float ah = bh[dA_] + s_g1[0][qA_][dA_]+s_g1[1][qA_][dA_]+s_g1[2][qA_][dA_]
                                + s_g1[3][qA_][dA_]+s_g1[4][qA_][dA_];
            float hh = ftanh_(ah);
            float pn = (1.f - zA_) * pA_ + zA_ * hh;
            s_pt[dA_][qA_] = pn;
            propW[(bi0+qA_)*DD + dA_] = pn;
            if (hasB) {
                float ahB = bh[dB_] + s_g1[0][qB_][dB_]+s_g1[1][qB_][dB_]+s_g1[2][qB_][dB_]
                                     + s_g1[3][qB_][dB_]+s_g1[4][qB_][dB_];
                float hhB = ftanh_(ahB);
                float pnB = (1.f - zB_) * pB_ + zB_ * hhB;
                s_pt[dB_][qB_] = pnB;
                propW[(bi0+qB_)*DD + dB_] = pnB;
            }
        }
        __syncthreads();
    }

    if (DO_A) {
        // ---- Phase A: wave g == expert g (balanced); lane-quad dq, lg k-sub ----
        const int e = g;
        float4 a0={0,0,0,0},a1={0,0,0,0},a2={0,0,0,0},a3={0,0,0,0},
               a4={0,0,0,0},a5={0,0,0,0},a6={0,0,0,0},a7={0,0,0,0};
        const int k0 = lg * 16;
        #pragma unroll 4
        for (int kk = 0; kk < 16; ++kk) {
            const int k = k0 + kk;
            float4 wv = *(const float4*)&We[((size_t)e*DD + k)*DD + dq];
            float4 pA = *(const float4*)&s_pt[k][0];
            float4 pB = *(const float4*)&s_pt[k][4];
            QFMA(a0,pA.x,wv) QFMA(a1,pA.y,wv) QFMA(a2,pA.z,wv) QFMA(a3,pA.w,wv)
            QFMA(a4,pB.x,wv) QFMA(a5,pB.y,wv) QFMA(a6,pB.z,wv) QFMA(a7,pB.w,wv)
        }
        QSHFL(a0,16) QSHFL(a1,16) QSHFL(a2,16) QSHFL(a3,16)
        QSHFL(a4,16) QSHFL(a5,16) QSHFL(a6,16) QSHFL(a7,16)
        QSHFL(a0,32) QSHFL(a1,32) QSHFL(a2,32) QSHFL(a3,32)
        QSHFL(a4,32) QSHFL(a5,32) QSHFL(a6,32) QSHFL(a7,32)
        if (lg == 0) {
            float4 bb = *(const float4*)&be[e*DD + dq];
            a0.x+=bb.x; a0.y+=bb.y; a0.z+=bb.z; a0.w+=bb.w;
            a1.x+=bb.x; a1.y+=bb.y; a1.z+=bb.z; a1.w+=bb.w;
            a2.x+=bb.x; a2.y+=bb.y; a2.z+=bb.z; a2.w+=bb.w;
            a3.x+=bb.x; a3.y+=bb.y; a3.z+=bb.z; a3.w+=bb.w;
            a4.x+=bb.x; a4.y+=bb.y; a4.z+=bb.z; a4.w+=bb.w;
            a5.x+=bb.x; a5.y+=bb.y; a5.z+=bb.z; a5.w+=bb.w;
            a6.x+=bb.x; a6.y+=bb.y; a6.z+=bb.z; a6.w+=bb.w;
            a7.x+=bb.x; a7.y+=bb.y; a7.z+=bb.z; a7.w+=bb.w;
            *(float4*)&msgW[((size_t)(bi0+0)*EE + e)*DD + dq] = a0;
            *(float4*)&msgW[((size_t)(bi0+1)*EE + e)*DD + dq] = a1;
            *(float4*)&msgW[((size_t)(bi0+2)*EE + e)*DD + dq] = a2;
            *(float4*)&msgW[((size_t)(bi0+3)*EE + e)*DD + dq] = a3;
            *(float4*)&msgW[((size_t)(bi0+4)*EE + e)*DD + dq] = a4;
            *(float4*)&msgW[((size_t)(bi0+5)*EE + e)*DD + dq] = a5;
            *(float4*)&msgW[((size_t)(bi0+6)*EE + e)*DD + dq] = a6;
            *(float4*)&msgW[((size_t)(bi0+7)*EE + e)*DD + dq] = a7;

            float4 war = *(const float4*)&Wa[e*2*DD + dq];
            float4 wac = *(const float4*)&Wa[e*2*DD + DD + dq];
            float rv0=QDOT(a0,war), rv1=QDOT(a1,war), rv2=QDOT(a2,war), rv3=QDOT(a3,war);
            float rv4=QDOT(a4,war), rv5=QDOT(a5,war), rv6=QDOT(a6,war), rv7=QDOT(a7,war);
            float cv0=QDOT(a0,wac), cv1=QDOT(a1,wac), cv2=QDOT(a2,wac), cv3=QDOT(a3,wac);
            float cv4=QDOT(a4,wac), cv5=QDOT(a5,wac), cv6=QDOT(a6,wac), cv7=QDOT(a7,wac);
            #pragma unroll
            for (int off = 1; off <= 8; off <<= 1) {
                rv0+=__shfl_xor(rv0,off); rv1+=__shfl_xor(rv1,off);
                rv2+=__shfl_xor(rv2,off); rv3+=__shfl_xor(rv3,off);
                rv4+=__shfl_xor(rv4,off); rv5+=__shfl_xor(rv5,off);
                rv6+=__shfl_xor(rv6,off); rv7+=__shfl_xor(rv7,off);
                cv0+=__shfl_xor(cv0,off); cv1+=__shfl_xor(cv1,off);
                cv2+=__shfl_xor(cv2,off); cv3+=__shfl_xor(cv3,off);
                cv4+=__shfl_xor(cv4,off); cv5+=__shfl_xor(cv5,off);
                cv6+=__shfl_xor(cv6,off); cv7+=__shfl_xor(cv7,off);
            }
            if (f == 0) {
                rowvW[(bi0+0)*EE+e]=rv0; rowvW[(bi0+1)*EE+e]=rv1;
                rowvW[(bi0+2)*EE+e]=rv2; rowvW[(bi0+3)*EE+e]=rv3;
                rowvW[(bi0+4)*EE+e]=rv4; rowvW[(bi0+5)*EE+e]=rv5;
                rowvW[(bi0+6)*EE+e]=rv6; rowvW[(bi0+7)*EE+e]=rv7;
                colvW[(bi0+0)*EE+e]=cv0; colvW[(bi0+1)*EE+e]=cv1;
                colvW[(bi0+2)*EE+e]=cv2; colvW[(bi0+3)*EE+e]=cv3;
                colvW[(bi0+4)*EE+e]=cv4; colvW[(bi0+5)*EE+e]=cv5;
                colvW[(bi0+6)*EE+e]=cv6; colvW[(bi0+7)*EE+e]=cv7;
            }
        }
    }
}

extern "C" void kernel_launch(void* const* d_in, const int* in_sizes, int n_in,
                              void* d_out, int out_size, void* d_ws, size_t ws_size,
                              hipStream_t stream)
{
    const float* inputs = (const float*)d_in[0];
    const int*   mask   = (const int*)d_in[1];
    const float* We     = (const float*)d_in[2];
    const float* be     = (const float*)d_in[3];
    const float* Wa     = (const float*)d_in[4];
    const float* ba     = (const float*)d_in[5];
    const float* Wr     = (const float*)d_in[6];
    const float* br     = (const float*)d_in[7];
    const float* Wz     = (const float*)d_in[8];
    const float* bz     = (const float*)d_in[9];
    const float* Wh     = (const float*)d_in[10];
    const float* bh     = (const float*)d_in[11];
    float* out = (float*)d_out;
    float* ws = (float*)d_ws;

    const int GRID = BB * NN / RR;   // 512
    const size_t need = (2*MSG_SZ + 3*COL_SZ + PROP_SZ) * sizeof(float);  // ~11.8 MB
    if (ws_size >= need) {
        float* msg0  = ws;
        float* msg1  = msg0 + MSG_SZ;
        float* colv0 = msg1 + MSG_SZ;
        float* colv1 = colv0 + COL_SZ;
        float* rowv  = colv1 + COL_SZ;
        float* prop  = rowv + COL_SZ;

        // prologue: PhaseA(0) only, prop source = inputs -> msg0/colv0
        k_iter<0,1><<<GRID, NTH, 0, stream>>>(
            inputs, prop, msg1, msg0, colv1, colv0, rowv, rowv, mask,
            We, be, Wa, ba, Wr, br, Wz, bz, Wh, bh, out);

        for (int t = 0; t < TT; ++t) {
            const float* msgR  = (t & 1) ? msg1 : msg0;
            float*       msgW  = (t & 1) ? msg0 : msg1;
            const float* colvR = (t & 1) ? colv1 : colv0;
            float*       colvW = (t & 1) ? colv0 : colv1;
            const float* propR = (t == 0) ? inputs : prop;
            float* out_t = out + (size_t)t * BB * NN * NE;
            if (t < TT - 1)
                k_iter<1,1><<<GRID, NTH, 0, stream>>>(
                    propR, prop, msgR, msgW, colvR, colvW, rowv, rowv, mask,
                    We, be, Wa, ba, Wr, br, Wz, bz, Wh, bh, out_t);
            else
                k_iter<1,0><<<GRID, NTH, 0, stream>>>(
                    propR, prop, msgR, msgW, colvR, colvW, rowv, rowv, mask,
                    We, be, Wa, ba, Wr, br, Wz, bz, Wh, bh, out_t);
        }
        return;
    }

    // ---- minimal-ws fallback: single buffers, B-only then A-only per iter ----
    float* prop = ws;
    float* msg  = prop + PROP_SZ;
    float* rowv = msg + MSG_SZ;
    float* colv = rowv + COL_SZ;
    k_iter<0,1><<<GRID, NTH, 0, stream>>>(
        inputs, prop, msg, msg, colv, colv, rowv, rowv, mask,
        We, be, Wa, ba, Wr, br, Wz, bz, Wh, bh, out);
    for (int t = 0; t < TT; ++t) {
        const float* propR = (t == 0) ? inputs : prop;
        float* out_t = out + (size_t)t * BB * NN * NE;
        k_iter<1,0><<<GRID, NTH, 0, stream>>>(
            propR, prop, msg, msg, colv, colv, rowv, rowv, mask,
            We, be, Wa, ba, Wr, br, Wz, bz, Wh, bh, out_t);
        if (t < TT - 1)
            k_iter<0,1><<<GRID, NTH, 0, stream>>>(
                prop, prop, msg, msg, colv, colv, rowv, rowv, mask,
                We, be, Wa, ba, Wr, br, Wz, bz, Wh, bh, out_t);
    }
}

// Round 13
// 196.554 us; speedup vs baseline: 1.6206x; 1.6206x over previous
//
#include <hip/hip_runtime.h>
#include <math.h>

#define BB 32
#define NN 128
#define DD 64
#define EE 5
#define TT 6          // 1+T iterations
#define NE (NN*EE)    // 640
#define RT 16         // rows per block
#define NTH 256       // 4 waves, wave = d-tile of 16

typedef __attribute__((ext_vector_type(8))) short bf16x8;
typedef __attribute__((ext_vector_type(4))) float f32x4;
typedef __attribute__((ext_vector_type(4))) unsigned short u16x4;

__device__ __forceinline__ unsigned short rneb(float x) {
    unsigned u = __float_as_uint(x);
    return (unsigned short)((u + 0x7fffu + ((u >> 16) & 1u)) >> 16);
}
__device__ __forceinline__ float b2f(unsigned short h) {
    return __uint_as_float(((unsigned)h) << 16);
}
__device__ __forceinline__ float fsig(float x) {
    float t = __expf(-x);
    return __fdividef(1.f, 1.f + t);
}
__device__ __forceinline__ float ftanh_(float x) {
    float xc = fminf(fmaxf(x, -15.f), 15.f);
    float t = __expf(-2.f * xc);
    return 1.f - __fdividef(2.f * t, 1.f + t);
}

// swizzled ushort-index: XOR byte bits 4-6  ->  ushort-index bits 3-5
#define SWZ(idx, row) ((idx) ^ (((row) & 7) << 3))

// ---------------- weight prep: bf16 transposed copies in ws ----------------
// WeT[e][d][k] = We[e][k][d];  W{r,z,h}T[d][k] = W{r,z,h}[k][d]
__global__ void wprep(const float* __restrict__ We, const float* __restrict__ Wr,
                      const float* __restrict__ Wz, const float* __restrict__ Wh,
                      unsigned short* __restrict__ WeT, unsigned short* __restrict__ WrT,
                      unsigned short* __restrict__ WzT, unsigned short* __restrict__ WhT)
{
    int idx = blockIdx.x * 256 + threadIdx.x;
    if (idx < EE * DD * DD) {                 // 20480
        int e = idx >> 12, rem = idx & 4095;
        int d = rem >> 6, k = rem & 63;
        WeT[idx] = rneb(We[e * DD * DD + k * DD + d]);
    }
    idx -= EE * DD * DD;
    if (idx >= 0 && idx < 3 * 2 * DD * DD) {  // 3 x 8192
        int m = idx >> 13, rem = idx & 8191;
        int d = rem >> 7, k = rem & 127;
        const float* W = (m == 0) ? Wr : (m == 1) ? Wz : Wh;
        unsigned short* WT = (m == 0) ? WrT : (m == 1) ? WzT : WhT;
        WT[rem] = rneb(W[k * DD + d]);
    }
}

// ---------------- per-iteration kernel (16 rows/block, MFMA) ----------------
// grid = 256 (1/CU), 256 thr. Wave g owns d-tile [g*16, g*16+16).
// XCD swizzle: batch b on XCD b%8.
template<int DO_B, int DO_A>
__global__ void __launch_bounds__(NTH) k_iter(
    const float* __restrict__ propR, float* __restrict__ propW,
    const unsigned short* __restrict__ msgTR, unsigned short* __restrict__ msgTW,
    const unsigned short* __restrict__ colvR, unsigned short* __restrict__ colvW,
    float* __restrict__ rowv,
    const int* __restrict__ mask,
    const unsigned short* __restrict__ WeT, const float* __restrict__ be,
    const float* __restrict__ Wa, const float* __restrict__ ba,
    const unsigned short* __restrict__ WrT, const float* __restrict__ br,
    const unsigned short* __restrict__ WzT, const float* __restrict__ bz,
    const unsigned short* __restrict__ WhT, const float* __restrict__ bh,
    float* __restrict__ out_t)
{
    const int bid = blockIdx.x;
    const int x = bid & 7;              // XCD
    const int s = bid >> 3;             // 0..31
    const int b = x + 8 * (s >> 3);     // 4 batches/XCD
    const int tile = s & 7;             // 8 tiles of 16 rows
    const int bi0 = b * NN + tile * RT;
    const int jt0 = tile * RT;          // j base within batch

    const int tid = threadIdx.x;
    const int g = tid >> 6;             // wave 0..3 = d-tile
    const int l = tid & 63;
    const int r16 = l & 15;             // A-row / B-col within tile
    const int h = l >> 4;               // k-chunk 0..3

    __shared__ unsigned short s_scb[RT * NE];    // 20 KB scores bf16 [i][e*128+j] swz
    __shared__ unsigned short s_a[RT * 2 * DD];  // 4 KB  [i][merged|prop->rpt] swz
    __shared__ unsigned short s_ptb[RT * DD];    // 2 KB  prop bf16 swz
    __shared__ float s_pt[RT][DD];               // 4 KB  prop f32
    __shared__ float s_cv[NE];                   // 2.5 KB colv f32 [e*128+j]
    __shared__ unsigned short s_mask[RT * NN];   // 4 KB
    __shared__ float s_rv[RT][EE];               // rowv + ba
    __shared__ float s_redr[EE][4][RT];          // rowv partials
    __shared__ float s_redc[EE][4][RT];          // colv partials

    // ---------------- phase 0: stage ----------------
    for (int idx = tid; idx < RT * DD; idx += NTH) {
        int row = idx >> 6, d = idx & 63;
        float v = propR[(bi0 + row) * DD + d];
        s_pt[row][d] = v;
        unsigned short sv = rneb(v);
        s_ptb[SWZ(row * DD + d, row)] = sv;
        s_a[SWZ(row * 2 * DD + DD + d, row)] = sv;   // prop half for r,z
    }
    if (DO_B) {
        for (int idx = tid; idx < NE; idx += NTH)
            s_cv[idx] = b2f(colvR[b * NE + idx]);
        for (int idx = tid; idx < RT * NN; idx += NTH)
            s_mask[idx] = (unsigned short)mask[(bi0 + (idx >> 7)) * NN + (idx & 127)];
        if (tid < RT * EE)
            s_rv[tid / EE][tid % EE] = rowv[(bi0 + tid / EE) * EE + tid % EE] + ba[tid % EE];
    }
    __syncthreads();

    f32x4 zv = {0.f, 0.f, 0.f, 0.f};

    if (DO_B) {
        // ---------------- phase 1: scores -> out + s_scb ----------------
        #pragma unroll 4
        for (int n = 0; n < RT * NE / NTH; ++n) {       // 40
            int idx = n * NTH + tid;
            int i = idx / NE, je = idx - i * NE;
            int j = je / EE, e = je - j * EE;
            float lg = s_rv[i][e] + s_cv[e * NN + j];
            float sc = fsig(lg) * (float)s_mask[i * NN + j];
            out_t[(size_t)(bi0 + i) * NE + je] = sc;
            s_scb[SWZ(i * NE + e * NN + j, i)] = rneb(sc);
        }
        __syncthreads();

        // ---------------- phase 2: merged MFMA (20 K-steps) ----------------
        {
            f32x4 acc = {0.f, 0.f, 0.f, 0.f};
            const unsigned short* mT = msgTR + ((size_t)b * DD + g * 16 + r16) * NE;
            #pragma unroll 4
            for (int st = 0; st < NE / 32; ++st) {
                int k0 = st * 32 + 8 * h;
                bf16x8 af = *(const bf16x8*)&s_scb[SWZ(r16 * NE + k0, r16)];
                bf16x8 bf = *(const bf16x8*)&mT[k0];
                acc = __builtin_amdgcn_mfma_f32_16x16x32_bf16(af, bf, acc, 0, 0, 0);
            }
            #pragma unroll
            for (int reg = 0; reg < 4; ++reg) {
                int row = 4 * h + reg, d = g * 16 + r16;
                s_a[SWZ(row * 2 * DD + d, row)] = rneb(acc[reg]);
            }
        }
        __syncthreads();

        // ---------------- phase 3: gates r,z MFMA + rpt ----------------
        {
            f32x4 ar = {0.f,0.f,0.f,0.f}, az = {0.f,0.f,0.f,0.f};
            const unsigned short* wr = WrT + (g * 16 + r16) * 2 * DD;
            const unsigned short* wz = WzT + (g * 16 + r16) * 2 * DD;
            #pragma unroll
            for (int st = 0; st < 4; ++st) {
                int k0 = st * 32 + 8 * h;
                bf16x8 af = *(const bf16x8*)&s_a[SWZ(r16 * 2 * DD + k0, r16)];
                bf16x8 bR = *(const bf16x8*)&wr[k0];
                bf16x8 bZ = *(const bf16x8*)&wz[k0];
                ar = __builtin_amdgcn_mfma_f32_16x16x32_bf16(af, bR, ar, 0, 0, 0);
                az = __builtin_amdgcn_mfma_f32_16x16x32_bf16(af, bZ, az, 0, 0, 0);
            }
            #pragma unroll
            for (int reg = 0; reg < 4; ++reg) {
                int row = 4 * h + reg, d = g * 16 + r16;
                float r = fsig(ar[reg] + br[d]);
                zv[reg] = fsig(az[reg] + bz[d]);
                s_a[SWZ(row * 2 * DD + DD + d, row)] = rneb(r * s_pt[row][d]);
            }
        }
        __syncthreads();

        // ---------------- phase 4: gate h MFMA + prop update ----------------
        {
            f32x4 ah = {0.f,0.f,0.f,0.f};
            const unsigned short* wh = WhT + (g * 16 + r16) * 2 * DD;
            #pragma unroll
            for (int st = 0; st < 4; ++st) {
                int k0 = st * 32 + 8 * h;
                bf16x8 af = *(const bf16x8*)&s_a[SWZ(r16 * 2 * DD + k0, r16)];
                bf16x8 bH = *(const bf16x8*)&wh[k0];
                ah = __builtin_amdgcn_mfma_f32_16x16x32_bf16(af, bH, ah, 0, 0, 0);
            }
            #pragma unroll
            for (int reg = 0; reg < 4; ++reg) {
                int row = 4 * h + reg, d = g * 16 + r16;
                float hh = ftanh_(ah[reg] + bh[d]);
                float p = s_pt[row][d];
                float pn = (1.f - zv[reg]) * p + zv[reg] * hh;
                s_pt[row][d] = pn;
                s_ptb[SWZ(row * DD + d, row)] = rneb(pn);
                propW[(size_t)(bi0 + row) * DD + d] = pn;
            }
        }
        __syncthreads();
    }

    if (DO_A) {
        // ---------------- phase 5: msg MFMA per expert + msgT/rowv/colv ----------------
        #pragma unroll
        for (int e = 0; e < EE; ++e) {
            f32x4 am = {0.f,0.f,0.f,0.f};
            const unsigned short* wt = WeT + ((size_t)e * DD + g * 16 + r16) * DD;
            #pragma unroll
            for (int st = 0; st < 2; ++st) {
                int k0 = st * 32 + 8 * h;
                bf16x8 af = *(const bf16x8*)&s_ptb[SWZ(r16 * DD + k0, r16)];
                bf16x8 bf = *(const bf16x8*)&wt[k0];
                am = __builtin_amdgcn_mfma_f32_16x16x32_bf16(af, bf, am, 0, 0, 0);
            }
            const int d = g * 16 + r16;
            const float beD = be[e * DD + d];
            float m0 = am[0] + beD, m1 = am[1] + beD, m2 = am[2] + beD, m3 = am[3] + beD;
            u16x4 pk; pk.x = rneb(m0); pk.y = rneb(m1); pk.z = rneb(m2); pk.w = rneb(m3);
            *(u16x4*)&msgTW[((size_t)b * DD + d) * NE + e * NN + jt0 + 4 * h] = pk;

            float war = Wa[e * 2 * DD + d], wac = Wa[e * 2 * DD + DD + d];
            float pr0 = m0 * war, pr1 = m1 * war, pr2 = m2 * war, pr3 = m3 * war;
            float pc0 = m0 * wac, pc1 = m1 * wac, pc2 = m2 * wac, pc3 = m3 * wac;
            #pragma unroll
            for (int off = 1; off <= 8; off <<= 1) {
                pr0 += __shfl_xor(pr0, off); pr1 += __shfl_xor(pr1, off);
                pr2 += __shfl_xor(pr2, off); pr3 += __shfl_xor(pr3, off);
                pc0 += __shfl_xor(pc0, off); pc1 += __shfl_xor(pc1, off);
                pc2 += __shfl_xor(pc2, off); pc3 += __shfl_xor(pc3, off);
            }
            if (r16 == 0) {
                s_redr[e][g][4 * h + 0] = pr0; s_redr[e][g][4 * h + 1] = pr1;
                s_redr[e][g][4 * h + 2] = pr2; s_redr[e][g][4 * h + 3] = pr3;
                s_redc[e][g][4 * h + 0] = pc0; s_redc[e][g][4 * h + 1] = pc1;
                s_redc[e][g][4 * h + 2] = pc2; s_redc[e][g][4 * h + 3] = pc3;
            }
        }
        __syncthreads();

        // ---------------- phase 6: reduce rowv/colv ----------------
        if (tid < EE * RT) {
            int e = tid >> 4, row = tid & 15;
            float rv = s_redr[e][0][row] + s_redr[e][1][row]
                     + s_redr[e][2][row] + s_redr[e][3][row];
            float cv = s_redc[e][0][row] + s_redc[e][1][row]
                     + s_redc[e][2][row] + s_redc[e][3][row];
            rowv[(bi0 + row) * EE + e] = rv;
            colvW[b * NE + e * NN + jt0 + row] = rneb(cv);
        }
    }
}

extern "C" void kernel_launch(void* const* d_in, const int* in_sizes, int n_in,
                              void* d_out, int out_size, void* d_ws, size_t ws_size,
                              hipStream_t stream)
{
    const float* inputs = (const float*)d_in[0];
    const int*   mask   = (const int*)d_in[1];
    const float* We     = (const float*)d_in[2];
    const float* be     = (const float*)d_in[3];
    const float* Wa     = (const float*)d_in[4];
    const float* ba     = (const float*)d_in[5];
    const float* Wr     = (const float*)d_in[6];
    const float* br     = (const float*)d_in[7];
    const float* Wz     = (const float*)d_in[8];
    const float* bz     = (const float*)d_in[9];
    const float* Wh     = (const float*)d_in[10];
    const float* bh     = (const float*)d_in[11];
    float* out = (float*)d_out;

    // ws layout (bytes), all 16B-aligned sizes
    char* p = (char*)d_ws;
    unsigned short* msgT0 = (unsigned short*)p; p += (size_t)BB * DD * NE * 2;  // 2.62 MB
    unsigned short* msgT1 = (unsigned short*)p; p += (size_t)BB * DD * NE * 2;
    unsigned short* colv0 = (unsigned short*)p; p += (size_t)BB * NE * 2;       // 41 KB
    unsigned short* colv1 = (unsigned short*)p; p += (size_t)BB * NE * 2;
    float* rowv = (float*)p;  p += (size_t)BB * NN * EE * 4;                    // 82 KB
    float* prop = (float*)p;  p += (size_t)BB * NN * DD * 4;                    // 1 MB
    unsigned short* WeT = (unsigned short*)p; p += EE * DD * DD * 2;            // 40 KB
    unsigned short* WrT = (unsigned short*)p; p += 2 * DD * DD * 2;             // 16 KB
    unsigned short* WzT = (unsigned short*)p; p += 2 * DD * DD * 2;
    unsigned short* WhT = (unsigned short*)p; p += 2 * DD * DD * 2;
    // total ~6.6 MB (< proven-available 11.8 MB)

    wprep<<<(EE*DD*DD + 3*2*DD*DD + 255) / 256, 256, 0, stream>>>(
        We, Wr, Wz, Wh, WeT, WrT, WzT, WhT);

    const int GRID = BB * NN / RT;   // 256

    // prologue: Phase A(0) from inputs -> msgT0/colv0/rowv
    k_iter<0,1><<<GRID, NTH, 0, stream>>>(
        inputs, prop, msgT1, msgT0, colv1, colv0, rowv, mask,
        WeT, be, Wa, ba, WrT, br, WzT, bz, WhT, bh, out);

    for (int t = 0; t < TT; ++t) {
        const unsigned short* msgR = (t & 1) ? msgT1 : msgT0;
        unsigned short*       msgW = (t & 1) ? msgT0 : msgT1;
        const unsigned short* cvR  = (t & 1) ? colv1 : colv0;
        unsigned short*       cvW  = (t & 1) ? colv0 : colv1;
        const float* propR = (t == 0) ? inputs : prop;
        float* out_t = out + (size_t)t * BB * NN * NE;
        if (t < TT - 1)
            k_iter<1,1><<<GRID, NTH, 0, stream>>>(
                propR, prop, msgR, msgW, cvR, cvW, rowv, mask,
                WeT, be, Wa, ba, WrT, br, WzT, bz, WhT, bh, out_t);
        else
            k_iter<1,0><<<GRID, NTH, 0, stream>>>(
                propR, prop, msgR, msgW, cvR, cvW, rowv, mask,
                WeT, be, Wa, ba, WrT, br, WzT, bz, WhT, bh, out_t);
    }
}